// Round 9
// baseline (173.047 us; speedup 1.0000x reference)
//
#include <hip/hip_runtime.h>

#define B_DIM 8192
#define NOUT  1024
#define KDIM  2048

typedef __bf16 bf16x8 __attribute__((ext_vector_type(8)));
typedef float  f32x4  __attribute__((ext_vector_type(4)));

__device__ __forceinline__ unsigned short f2bf(float f) {
  unsigned int u = __float_as_uint(f);
  u += 0x7fff + ((u >> 16) & 1);   // RNE
  return (unsigned short)(u >> 16);
}
__device__ __forceinline__ float sigmoid_f(float x) {
  return 1.0f / (1.0f + __expf(-x));
}
__device__ __forceinline__ float tanh_f(float x) {
  return 1.0f - 2.0f / (__expf(2.0f * x) + 1.0f);
}
__device__ __forceinline__ void gload_lds16(const void* g, void* l) {
  __builtin_amdgcn_global_load_lds(
      (const __attribute__((address_space(1))) void*)g,
      (__attribute__((address_space(3))) void*)l, 16, 0, 0);
}

// gate-interleaved weight column index: 64-ci group = 16 nouts x 4 gates,
// so ONE wave's 64-ci strip holds all 4 gates of 16 nouts (ni index = gate).
__device__ __forceinline__ int cimap(int g, int n) {
  return ((n >> 4) << 6) | ((g & 3) << 4) | (n & 15);
}

// ---------------- kernel 1: pack xh = concat(x, out_tm1) as bf16 ------------
__global__ void pack_xh_kernel(const float* __restrict__ x,
                               const float* __restrict__ h,
                               unsigned short* __restrict__ xh) {
  const long total = (long)B_DIM * KDIM / 4;
  for (long i = (long)blockIdx.x * blockDim.x + threadIdx.x; i < total;
       i += (long)gridDim.x * blockDim.x) {
    long e = i * 4;
    int b = (int)(e >> 11);
    int c = (int)(e & 2047);
    float4 v = (c < 1024)
        ? *reinterpret_cast<const float4*>(x + (long)b * 1024 + c)
        : *reinterpret_cast<const float4*>(h + (long)b * 1024 + (c - 1024));
    ushort4 o;
    o.x = f2bf(v.x); o.y = f2bf(v.y); o.z = f2bf(v.z); o.w = f2bf(v.w);
    *reinterpret_cast<ushort4*>(xh + e) = o;
  }
}

// ------- kernel 2: wt[ci][k] = bf16(W_g[k][n]), ci = gate-interleaved -------
__global__ void transpose_w_kernel(const float* __restrict__ Wf,
                                   const float* __restrict__ Wi,
                                   const float* __restrict__ Wc,
                                   const float* __restrict__ Wo,
                                   unsigned short* __restrict__ wt) {
  __shared__ float tile[32][33];
  const int g = blockIdx.z;
  const float* W = (g == 0) ? Wf : (g == 1) ? Wi : (g == 2) ? Wc : Wo;
  const int n0 = blockIdx.x * 32;
  const int k0 = blockIdx.y * 32;
  const int tx = threadIdx.x, ty = threadIdx.y;
#pragma unroll
  for (int r = ty; r < 32; r += 8)
    tile[r][tx] = W[(long)(k0 + r) * NOUT + n0 + tx];
  __syncthreads();
#pragma unroll
  for (int r = ty; r < 32; r += 8) {
    int ci = cimap(g, n0 + r);
    wt[(long)ci * KDIM + k0 + tx] = f2bf(tile[tx][r]);
  }
}

// --- kernel 3: 128m x 256ci GEMM, BK=32, ring-3 LDS, 2 blocks/CU ----------
// Block: 256 threads = 4 waves; wave tile = 128m x 64ci (wn = wave).
// LDS: 3 slots x (A 8 KB + B 16 KB) = 72 KB -> 2 independent blocks/CU.
// Per K32-iter t (slot = t%3):
//   { 12 ds_reads(slot t) ; 6 gload_lds stage(t+2 -> slot (t+2)%3) ;
//     s_waitcnt vmcnt(6) lgkmcnt(0) ; s_barrier ; setprio ; 32 MFMA }
// RAW: vmcnt(6) leaves only stage(t+2)'s 6 outstanding => stage(t+1)
//   retired pre-BAR(t) => visible to all at BAR(t), one barrier before
//   ITER(t+1)'s reads.  (Prologue: stage(0),stage(1); vmcnt(6); BAR.)
// WAR: lgkmcnt(0) pre-barrier pins reads(t) serviced before BAR(t)-arrival;
//   the overwrite of slot(t) is stage(t+3) issued in ITER(t+1), i.e. after
//   BAR(t) release >= all waves' pinned reads.  Airtight (no timing margin
//   assumptions -- fixes the latent WAR window in rounds 4/6).
// Tail: ITER(62) re-stages k=63 into slot1 (never read again, harmless).
__device__ __forceinline__ void stage6(const char* xh_b, const char* wt_b,
                                       long aoff, long boff, int kt,
                                       char* lds, int sbase, int tid) {
  const long kb = (long)kt * 64;
#pragma unroll
  for (int r = 0; r < 2; ++r)
    gload_lds16(xh_b + aoff + (long)r * 64 * 4096 + kb,
                lds + sbase + r * 4096 + tid * 16);
#pragma unroll
  for (int r = 0; r < 4; ++r)
    gload_lds16(wt_b + boff + (long)r * 64 * 4096 + kb,
                lds + sbase + 8192 + r * 4096 + tid * 16);
}

#define LOAD_FRAGS(S)                                                       \
  _Pragma("unroll") for (int mi = 0; mi < 8; ++mi)                          \
    af[mi] = *reinterpret_cast<const bf16x8*>(                              \
        lds + (S)*24576 + mi * 1024 + rdoff);                               \
  _Pragma("unroll") for (int ni = 0; ni < 4; ++ni)                          \
    bq[ni] = *reinterpret_cast<const bf16x8*>(                              \
        lds + (S)*24576 + 8192 + wn * 4096 + ni * 1024 + rdoff);

#define MFMA32()                                                            \
  _Pragma("unroll") for (int mi = 0; mi < 8; ++mi)                          \
  _Pragma("unroll") for (int ni = 0; ni < 4; ++ni)                          \
    acc[mi][ni] = __builtin_amdgcn_mfma_f32_16x16x32_bf16(                  \
        af[mi], bq[ni], acc[mi][ni], 0, 0, 0);

#define ITER(RS, WS, KST)                                                   \
  LOAD_FRAGS(RS)                                                            \
  stage6(xh_b, wt_b, aoff, boff, (KST), lds, (WS)*24576, tid);              \
  asm volatile("s_waitcnt vmcnt(6) lgkmcnt(0)" ::: "memory");               \
  __builtin_amdgcn_sched_barrier(0);                                        \
  __builtin_amdgcn_s_barrier();                                             \
  __builtin_amdgcn_sched_barrier(0);                                        \
  __builtin_amdgcn_s_setprio(1);                                            \
  MFMA32()                                                                  \
  __builtin_amdgcn_s_setprio(0);                                            \
  __builtin_amdgcn_sched_barrier(0);

__global__ __launch_bounds__(256, 2)
void lstm_gemm_kernel(const unsigned short* __restrict__ xh,
                      const unsigned short* __restrict__ wt,
                      const float* __restrict__ state,
                      const float* __restrict__ bfp,
                      const float* __restrict__ bip,
                      const float* __restrict__ bcp,
                      const float* __restrict__ bop,
                      float* __restrict__ out) {
  __shared__ __attribute__((aligned(128))) char lds[73728];   // 3 x 24 KB

  const int tid  = threadIdx.x;
  const int lane = tid & 63;
  const int wn   = tid >> 6;        // wave = ci strip 0..3

  // XCD map: xcd k owns ci-block pair {2k,2k+1} (B slab 2 MB, L2-resident);
  // within an XCD, consecutive j walk m-bands (A-band 512 KB, L2-reused).
  const int wgid = blockIdx.y * 16 + blockIdx.x;   // 1024 blocks
  const int j    = wgid >> 3;
  const int xcd  = wgid & 7;
  const int bx   = (xcd << 1) | (j & 1);           // ci-block 0..15
  const int by   = j >> 1;                         // m-block  0..63
  const long m0  = (long)by * 128;
  const long c0  = (long)bx * 256;

  // --- staging addressing (rule 21: pre-swizzled SOURCE, linear LDS dest) --
  // LDS rows are 64 B (BK=32). Write: thread t -> row rsub=t>>2, lin granule
  // t&3, so source granule = (t&3) ^ (rsub&3).
  const int  rsub = tid >> 2;
  const int  gsw  = ((tid & 3) ^ (rsub & 3)) << 4;
  const long aoff = (m0 + rsub) * 4096 + gsw;
  const long boff = (c0 + rsub) * 4096 + gsw;

  // --- fragment read addressing: row = 16*mi + (l&15) (row&3 == l&3),
  // k-granule g = l>>4, swizzled lin = g ^ (l&3).
  const int rdoff = (lane & 15) * 64 + (((lane >> 4) ^ (lane & 3)) << 4);

  const char* xh_b = (const char*)xh;  // 4096 B rows
  const char* wt_b = (const char*)wt;  // 4096 B rows

  f32x4  acc[8][4] = {};   // [mi 0..7][ni = gate f,i,c,o]
  bf16x8 af[8];
  bf16x8 bq[4];

  // ---- prologue: stage k-tiles 0,1 into slots 0,1; retire slot0; barrier
  stage6(xh_b, wt_b, aoff, boff, 0, lds, 0,     tid);
  stage6(xh_b, wt_b, aoff, boff, 1, lds, 24576, tid);
  asm volatile("s_waitcnt vmcnt(6)" ::: "memory");
  __builtin_amdgcn_sched_barrier(0);
  __builtin_amdgcn_s_barrier();
  __builtin_amdgcn_sched_barrier(0);

  // ---- main loop: t = 0..62, unrolled x3 for compile-time slot offsets
  for (int t = 0; t < 63; t += 3) {
    const int k2 = t + 2;                          // <= 62? t<=60 -> 62 max
    const int k3 = (t + 3 > 63) ? 63 : t + 3;
    const int k4 = (t + 4 > 63) ? 63 : t + 4;
    ITER(0, 2, k2)
    ITER(1, 0, k3)
    ITER(2, 1, k4)
  }
  // ---- tail: t = 63 reads slot 0 (staged at t=61, retired at t=62's VM6)
  LOAD_FRAGS(0)
  asm volatile("s_waitcnt lgkmcnt(0)" ::: "memory");
  __builtin_amdgcn_sched_barrier(0);
  __builtin_amdgcn_s_setprio(1);
  MFMA32()
  __builtin_amdgcn_s_setprio(0);
  asm volatile("s_waitcnt vmcnt(0)" ::: "memory");  // drain dup stages

  // ---- fused LSTM epilogue: 4 gates = the 4 ni fragments, lane-local
  const int   nout = (bx * 4 + wn) * 16 + (lane & 15);
  const int   rsub4 = (lane >> 4) << 2;
  const float bfv = bfp[nout], biv = bip[nout];
  const float bcv = bcp[nout], bov = bop[nout];
  float* out2 = out + (long)B_DIM * NOUT;
#pragma unroll
  for (int mi = 0; mi < 8; ++mi)
#pragma unroll
    for (int v = 0; v < 4; ++v) {
      const long row = m0 + mi * 16 + rsub4 + v;
      float fg = sigmoid_f(acc[mi][0][v] + bfv);
      float ig = sigmoid_f(acc[mi][1][v] + biv);
      float cg = tanh_f   (acc[mi][2][v] + bcv);
      float og = sigmoid_f(acc[mi][3][v] + bov);
      float st = state[row * NOUT + nout];
      float ns = st * fg + ig * cg;
      out [row * NOUT + nout] = og * tanh_f(ns);
      out2[row * NOUT + nout] = ns;
    }
}

extern "C" void kernel_launch(void* const* d_in, const int* in_sizes, int n_in,
                              void* d_out, int out_size, void* d_ws, size_t ws_size,
                              hipStream_t stream) {
  const float* x     = (const float*)d_in[0];
  const float* h     = (const float*)d_in[1];
  const float* state = (const float*)d_in[2];
  const float* Wf    = (const float*)d_in[3];
  const float* bfp   = (const float*)d_in[4];
  const float* Wi    = (const float*)d_in[5];
  const float* bip   = (const float*)d_in[6];
  const float* Wc    = (const float*)d_in[7];
  const float* bcp   = (const float*)d_in[8];
  const float* Wo    = (const float*)d_in[9];
  const float* bop   = (const float*)d_in[10];
  float* out = (float*)d_out;

  unsigned short* xh = (unsigned short*)d_ws;
  unsigned short* wt = (unsigned short*)((char*)d_ws + (size_t)B_DIM * KDIM * 2);

  hipLaunchKernelGGL(pack_xh_kernel, dim3(2048), dim3(256), 0, stream, x, h, xh);
  hipLaunchKernelGGL(transpose_w_kernel, dim3(NOUT / 32, KDIM / 32, 4),
                     dim3(32, 8), 0, stream, Wf, Wi, Wc, Wo, wt);
  hipLaunchKernelGGL(lstm_gemm_kernel, dim3(16, 64), dim3(256), 0, stream,
                     xh, wt, state, bfp, bip, bcp, bop, out);
}

// Round 10
// 160.919 us; speedup vs baseline: 1.0754x; 1.0754x over previous
//
#include <hip/hip_runtime.h>

#define B_DIM 8192
#define NOUT  1024
#define KDIM  2048

typedef __bf16 bf16x8 __attribute__((ext_vector_type(8)));
typedef float  f32x4  __attribute__((ext_vector_type(4)));

__device__ __forceinline__ unsigned short f2bf(float f) {
  unsigned int u = __float_as_uint(f);
  u += 0x7fff + ((u >> 16) & 1);   // RNE
  return (unsigned short)(u >> 16);
}
__device__ __forceinline__ float sigmoid_f(float x) {
  return 1.0f / (1.0f + __expf(-x));
}
__device__ __forceinline__ float tanh_f(float x) {
  return 1.0f - 2.0f / (__expf(2.0f * x) + 1.0f);
}
__device__ __forceinline__ void gload_lds16(const void* g, void* l) {
  __builtin_amdgcn_global_load_lds(
      (const __attribute__((address_space(1))) void*)g,
      (__attribute__((address_space(3))) void*)l, 16, 0, 0);
}

// gate-interleaved weight column index (round-2/4/6 mapping, verified)
__device__ __forceinline__ int cimap(int g, int n) {
  return ((n >> 6) << 8) | ((g >> 1) << 7) | (((n >> 4) & 3) << 5) |
         ((g & 1) << 4) | (n & 15);
}

// ---------------- kernel 1: pack xh = concat(x, out_tm1) as bf16 ------------
__global__ void pack_xh_kernel(const float* __restrict__ x,
                               const float* __restrict__ h,
                               unsigned short* __restrict__ xh) {
  const long total = (long)B_DIM * KDIM / 4;
  for (long i = (long)blockIdx.x * blockDim.x + threadIdx.x; i < total;
       i += (long)gridDim.x * blockDim.x) {
    long e = i * 4;
    int b = (int)(e >> 11);
    int c = (int)(e & 2047);
    float4 v = (c < 1024)
        ? *reinterpret_cast<const float4*>(x + (long)b * 1024 + c)
        : *reinterpret_cast<const float4*>(h + (long)b * 1024 + (c - 1024));
    ushort4 o;
    o.x = f2bf(v.x); o.y = f2bf(v.y); o.z = f2bf(v.z); o.w = f2bf(v.w);
    *reinterpret_cast<ushort4*>(xh + e) = o;
  }
}

// ------- kernel 2: wt[ci][k] = bf16(W_g[k][n]), ci = gate-interleaved -------
__global__ void transpose_w_kernel(const float* __restrict__ Wf,
                                   const float* __restrict__ Wi,
                                   const float* __restrict__ Wc,
                                   const float* __restrict__ Wo,
                                   unsigned short* __restrict__ wt) {
  __shared__ float tile[32][33];
  const int g = blockIdx.z;
  const float* W = (g == 0) ? Wf : (g == 1) ? Wi : (g == 2) ? Wc : Wo;
  const int n0 = blockIdx.x * 32;
  const int k0 = blockIdx.y * 32;
  const int tx = threadIdx.x, ty = threadIdx.y;
#pragma unroll
  for (int r = ty; r < 32; r += 8)
    tile[r][tx] = W[(long)(k0 + r) * NOUT + n0 + tx];
  __syncthreads();
#pragma unroll
  for (int r = ty; r < 32; r += 8) {
    int ci = cimap(g, n0 + r);
    wt[(long)ci * KDIM + k0 + tx] = f2bf(tile[tx][r]);
  }
}

// --- kernel 3: 256x256 tile, BK=32, ring-3 LDS, 1 barrier/K-tile + LSTM ----
// LDS layout (per 32 KB slot): A tile 16 KB then B tile 16 KB. Two 64-B rows
// pack one 128-B line; (row r, 16B-granule g) lives at line = r>>1,
// slot8 = (((r&1)<<2) | g) ^ (line & 7).   Bank spread for reads
// (row = 16*mi + (l&15), g = l>>4): slot8(l) = ((l&1)<<2 | l>>4) ^ ((l>>1)&7)
// -> exactly 8 lanes per 16-B slot across all 32 banks (same uniform spread
// as the verified R4/R6 128B-row swizzle; fixes R9's 8-way conflict).
//
// Per K-tile t (slot RS = t%3, stage WS = (t+2)%3), ONE barrier:
//   { 12 ds_read_b128 ; 4 gload_lds stage(t+2) ; 32 MFMA  (compiler-
//     scheduled region, fine-grained lgkm auto-inserted) ;
//     s_waitcnt vmcnt(4) lgkmcnt(0) ; s_barrier }
// RAW: VM4 leaves only stage(t+2)'s 4 outstanding => stage(t+1) retired one
//   barrier before tile t+1's reads. Prologue: stage(0),stage(1); VM4; BAR.
// WAR: stage(t+2) overwrites slot (t-1)%3; reads(t-1) are lgkm-pinned before
//   BAR(t-1); stage(t+2) issues after BAR(t-1) release. Airtight.
// Tail: t=62 stages clamped k=63 dup into slot1 (never read); t=63 has no
//   stage; VM0 drains before epilogue.
#define SB() __builtin_amdgcn_sched_barrier(0);

#define LOAD_AF(S, MQ)                                                      \
  _Pragma("unroll") for (int mi = 0; mi < 4; ++mi)                          \
    af[mi] = *reinterpret_cast<const bf16x8*>(                              \
        lds + (S)*32768 + (MQ)*8192 + laneA + mi*1024);

#define LOAD_BQ(S, NQ, DST)                                                 \
  _Pragma("unroll") for (int ni = 0; ni < 2; ++ni)                          \
    DST[ni] = *reinterpret_cast<const bf16x8*>(                             \
        lds + (S)*32768 + 16384 + (NQ)*8192 + laneB + ni*1024);

#define STAGE4(WS, KT)                                                      \
  gload_lds16(xh_b + (m0 + 0   + rsrc)*4096 + (long)(KT)*64 + csrc,         \
              lds + (WS)*32768 + 0     + wave*1024);                        \
  gload_lds16(xh_b + (m0 + 128 + rsrc)*4096 + (long)(KT)*64 + csrc,         \
              lds + (WS)*32768 + 8192  + wave*1024);                        \
  gload_lds16(wt_b + (c0 + 0   + rsrc)*4096 + (long)(KT)*64 + csrc,         \
              lds + (WS)*32768 + 16384 + wave*1024);                        \
  gload_lds16(wt_b + (c0 + 128 + rsrc)*4096 + (long)(KT)*64 + csrc,         \
              lds + (WS)*32768 + 24576 + wave*1024);

#define MFMA8(MQ, NQ, BQ)                                                   \
  _Pragma("unroll") for (int mi = 0; mi < 4; ++mi)                          \
  _Pragma("unroll") for (int ni = 0; ni < 2; ++ni)                          \
    acc[MQ][NQ][mi][ni] = __builtin_amdgcn_mfma_f32_16x16x32_bf16(          \
        af[mi], BQ[ni], acc[MQ][NQ][mi][ni], 0, 0, 0);

#define ITER(RS, WS, KT)                                                    \
  LOAD_AF(RS, 0)                                                            \
  LOAD_BQ(RS, 0, bq0)                                                       \
  LOAD_BQ(RS, 1, bq1)                                                       \
  STAGE4(WS, KT)                                                            \
  __builtin_amdgcn_s_setprio(1);                                            \
  MFMA8(0, 0, bq0)                                                          \
  MFMA8(0, 1, bq1)                                                          \
  LOAD_AF(RS, 1)                                                            \
  MFMA8(1, 1, bq1)                                                          \
  MFMA8(1, 0, bq0)                                                          \
  __builtin_amdgcn_s_setprio(0);                                            \
  asm volatile("s_waitcnt vmcnt(4) lgkmcnt(0)" ::: "memory");               \
  SB()                                                                      \
  __builtin_amdgcn_s_barrier();                                             \
  SB()

__global__ __launch_bounds__(512, 2)
void lstm_gemm_kernel(const unsigned short* __restrict__ xh,
                      const unsigned short* __restrict__ wt,
                      const float* __restrict__ state,
                      const float* __restrict__ bfp,
                      const float* __restrict__ bip,
                      const float* __restrict__ bcp,
                      const float* __restrict__ bop,
                      float* __restrict__ out) {
  __shared__ __attribute__((aligned(128))) char lds[98304];   // 3 x 32 KB

  const int tid  = threadIdx.x;
  const int wave = tid >> 6;
  const int lane = tid & 63;
  const int wm = wave >> 2;     // 0..1 : 64-row strip
  const int wn = wave & 3;      // 0..3 : 32-ci strip

  // XCD-aware swizzle (nwg = 512, divisible by 8; R6-verified)
  int wg = blockIdx.y * 16 + blockIdx.x;
  wg = (wg & 7) * 64 + (wg >> 3);
  const int  bm = wg >> 4;      // 0..31
  const int  bn = wg & 15;      // 0..15
  const long m0 = (long)bm * 256;
  const long c0 = (long)bn * 256;

  // ---- read addressing (derivation in header comment) ----
  const int lrow   = lane & 15;
  const int key    = (lane >> 1) & 7;
  const int slotsw = (((lane & 1) << 2) | (lane >> 4)) ^ key;   // 0..7
  const int laneRC = key * 128 + slotsw * 16;
  const int laneA  = wm * 4096 + laneRC;   // + MQ*8192 + mi*1024
  const int laneB  = wn * 2048 + laneRC;   // + NQ*8192 + ni*1024

  // ---- stage addressing: dest linear 16B/thread; inverse-swizzled SOURCE.
  // dest byte = p*8192 + t*16 -> line = t>>3, slot = t&7;
  // v = slot ^ (line&7); src row = p*128 + (t>>3)*2 + (v>>2), col = (v&3)*16.
  const int vsw  = (lane & 7) ^ ((lane >> 3) & 7);
  const long rsrc = wave * 16 + (lane >> 3) * 2 + (vsw >> 2);
  const int  csrc = (vsw & 3) * 16;

  const char* xh_b = (const char*)xh;  // 4096 B rows
  const char* wt_b = (const char*)wt;  // 4096 B rows

  f32x4  acc[2][2][4][2] = {};
  bf16x8 af[4];
  bf16x8 bq0[2];
  bf16x8 bq1[2];

  // ---- prologue: stage k-tiles 0,1 into slots 0,1; retire tile0; barrier
  STAGE4(0, 0)
  STAGE4(1, 1)
  asm volatile("s_waitcnt vmcnt(4)" ::: "memory");
  SB()
  __builtin_amdgcn_s_barrier();
  SB()

  // ---- main loop: tiles 0..62 (21 x 3-unrolled), tail tile 63
  for (int t = 0; t < 63; t += 3) {
    const int k4 = (t + 4 > 63) ? 63 : t + 4;
    ITER(0, 2, t + 2)
    ITER(1, 0, t + 3)
    ITER(2, 1, k4)
  }
  // tail: tile 63 reads slot 0 (staged by t=61, retired by t=62's VM4)
  LOAD_AF(0, 0)
  LOAD_BQ(0, 0, bq0)
  LOAD_BQ(0, 1, bq1)
  __builtin_amdgcn_s_setprio(1);
  MFMA8(0, 0, bq0)
  MFMA8(0, 1, bq1)
  LOAD_AF(0, 1)
  MFMA8(1, 1, bq1)
  MFMA8(1, 0, bq0)
  __builtin_amdgcn_s_setprio(0);
  asm volatile("s_waitcnt vmcnt(0) lgkmcnt(0)" ::: "memory");  // drain stages
  SB()

  // ---- fused LSTM epilogue: lane's 4 n-frags are the 4 gates of column nout
  const int   nout = bn * 64 + wn * 16 + lrow;     // 0..1023
  const int   rsub4 = (lane >> 4) << 2;
  const float bfv = bfp[nout], biv = bip[nout];
  const float bcv = bcp[nout], bov = bop[nout];
  float* out2 = out + (long)B_DIM * NOUT;
#pragma unroll
  for (int mq = 0; mq < 2; ++mq)
#pragma unroll
    for (int mi = 0; mi < 4; ++mi)
#pragma unroll
      for (int v = 0; v < 4; ++v) {
        const long row = m0 + mq * 128 + wm * 64 + mi * 16 + rsub4 + v;
        float fg = sigmoid_f(acc[mq][0][mi][0][v] + bfv);
        float ig = sigmoid_f(acc[mq][0][mi][1][v] + biv);
        float cg = tanh_f   (acc[mq][1][mi][0][v] + bcv);
        float og = sigmoid_f(acc[mq][1][mi][1][v] + bov);
        float st = state[row * NOUT + nout];
        float ns = st * fg + ig * cg;
        out [row * NOUT + nout] = og * tanh_f(ns);
        out2[row * NOUT + nout] = ns;
      }
}

extern "C" void kernel_launch(void* const* d_in, const int* in_sizes, int n_in,
                              void* d_out, int out_size, void* d_ws, size_t ws_size,
                              hipStream_t stream) {
  const float* x     = (const float*)d_in[0];
  const float* h     = (const float*)d_in[1];
  const float* state = (const float*)d_in[2];
  const float* Wf    = (const float*)d_in[3];
  const float* bfp   = (const float*)d_in[4];
  const float* Wi    = (const float*)d_in[5];
  const float* bip   = (const float*)d_in[6];
  const float* Wc    = (const float*)d_in[7];
  const float* bcp   = (const float*)d_in[8];
  const float* Wo    = (const float*)d_in[9];
  const float* bop   = (const float*)d_in[10];
  float* out = (float*)d_out;

  unsigned short* xh = (unsigned short*)d_ws;
  unsigned short* wt = (unsigned short*)((char*)d_ws + (size_t)B_DIM * KDIM * 2);

  hipLaunchKernelGGL(pack_xh_kernel, dim3(2048), dim3(256), 0, stream, x, h, xh);
  hipLaunchKernelGGL(transpose_w_kernel, dim3(NOUT / 32, KDIM / 32, 4),
                     dim3(32, 8), 0, stream, Wf, Wi, Wc, Wo, wt);
  hipLaunchKernelGGL(lstm_gemm_kernel, dim3(16, 32), dim3(512), 0, stream,
                     xh, wt, state, bfp, bip, bcp, bop, out);
}